// Round 15
// baseline (5718.065 us; speedup 1.0000x reference)
//
#include <hip/hip_runtime.h>
#include <stdint.h>

// Farthest point sampling: b=16, n=65536, npoints=2048. Full-f64 decision
// pipeline (R5: harness ref is float64 ground-truth recompute).
//
// R31 = R23 (4.26 ms, best proven) + ADAPTIVE poll-sleep controller.
// R30 audit: VGPR=84 = 48 f32 coords + 32 f64 dist + temps -- compiler
// keeps coords f32 and re-widens (~100-190cy/iter, minor), update is
// ~1000-1400cy, so the rendezvous wait is ~3600cy/iter. Its structure:
// straggler-visible time V + first-poll ALIGNMENT ERROR + RT(~1000-1300,
// 16-line gather). With fixed sleep 768cy and V~1500-2500, detection lands
// on round 2-3 -> 1-2 whole RTs of quantization paid every iteration.
// Fix WITHOUT extra traffic (R12/R27 law) and WITHOUT a global clock
// (R29's dead end): feedback-tune the sleep so the first poll lands just
// after V. Controller (wave0, wave-uniform): hit-on-round-1 -> slp -= 1
// (64cy probe down); any miss -> slp += 14 (~1 RT). Converges to the
// max-V edge, tracks drift, decays transients. Poll loop made
// wave-uniform (all lanes reload until __all(ok)) so the round count is
// uniform -- identical traffic in the converged 1-round regime. slp
// bounded [2,44]; pure timing change, correctness untouched.
// Tripwires: WRITE_SIZE exactly 65632 KB; absmax 0. Neutral result =>
// detection was already round-1-optimal => structure is at its latency
// floor (transit + RT).
//
// Protocol (R23, proven): 16 blocks x 256 thr per batch; pre-widened f64
// coords; DPP/permlane argmax butterflies; per-wave publish of 16B
// quarters via atomic_swap_x2 (single writer per word); wave0 polls 64
// quarters (lane i watches quarter i, own-quarter register substitution);
// speculative P[] coord prefetch + ballot(si==ci) + readlane broadcast;
// waves1-3 spin on 3 self-tagged LDS coord words; parity double-buffer;
// unique 16-bit tags (poison 0 unmatchable); skew<=1; all spins guarded.

#define NBATCH   16
#define NPTS     65536
#define NPOINTS  2048
#define KBLK     16                  // blocks per batch
#define THREADS  256
#define PPB      4096                // points per block
#define PPT      16                  // points per thread
#define QPB      4                   // quarters (waves) per block
#define SLOT_U64 2                   // 16 B per wave-quarter
#define REGION_U64 (KBLK * QPB * SLOT_U64) // 128 u64 = 1 KB per (parity,batch)

#define TAGOK(w) (((unsigned)((w) >> 16) & 0xFFFFu) == tag)

typedef unsigned int uint4v __attribute__((ext_vector_type(4)));
typedef unsigned int uint2v __attribute__((ext_vector_type(2)));
typedef unsigned long long ull;

// One 16-B device-scope load covering both quarter words.
__device__ __forceinline__ void load_slot16(const ull* p, ull& w0, ull& w1) {
    uint4v r;
    asm volatile("global_load_dwordx4 %0, %1, off sc1\n\t"
                 "s_waitcnt vmcnt(0)"
                 : "=v"(r) : "v"(p) : "memory");
    w0 = ((ull)r.y << 32) | r.x;
    w1 = ((ull)r.w << 32) | r.z;
}

// ---- argmax butterfly stages: (d,i) <- winner of self and partner ----
__device__ __forceinline__ void red_combine(double& d, int& i,
                                            double od, int oi) {
    const bool t = (od > d) || (od == d && oi < i);
    d = t ? od : d; i = t ? oi : i;
}

template <int CTRL>
__device__ __forceinline__ void red_dpp(double& d, int& i) {
    const int hi = __double2hiint(d), lo = __double2loint(d);
    const int ohi = __builtin_amdgcn_update_dpp(hi, hi, CTRL, 0xF, 0xF, false);
    const int olo = __builtin_amdgcn_update_dpp(lo, lo, CTRL, 0xF, 0xF, false);
    const int oi  = __builtin_amdgcn_update_dpp(i,  i,  CTRL, 0xF, 0xF, false);
    red_combine(d, i, __hiloint2double(ohi, olo), oi);
}

__device__ __forceinline__ void red_swz16(double& d, int& i) {
    // ds_swizzle BitMode xor16: offset = (16<<10) | 0x1F = 0x401F
    const int ohi = __builtin_amdgcn_ds_swizzle(__double2hiint(d), 0x401F);
    const int olo = __builtin_amdgcn_ds_swizzle(__double2loint(d), 0x401F);
    const int oi  = __builtin_amdgcn_ds_swizzle(i, 0x401F);
    red_combine(d, i, __hiloint2double(ohi, olo), oi);
}

__device__ __forceinline__ void red_x32(double& d, int& i, bool hi_half) {
    // permlane32_swap(v,v): partner = hi_half ? r[0] : r[1].
    const unsigned hi = (unsigned)__double2hiint(d);
    const unsigned lo = (unsigned)__double2loint(d);
    uint2v rh = __builtin_amdgcn_permlane32_swap(hi, hi, false, false);
    uint2v rl = __builtin_amdgcn_permlane32_swap(lo, lo, false, false);
    uint2v ri = __builtin_amdgcn_permlane32_swap((unsigned)i, (unsigned)i,
                                                 false, false);
    const int ohi = (int)(hi_half ? rh[0] : rh[1]);
    const int olo = (int)(hi_half ? rl[0] : rl[1]);
    const int oi  = (int)(hi_half ? ri[0] : ri[1]);
    red_combine(d, i, __hiloint2double(ohi, olo), oi);
}

// Full 64-lane argmax (all lanes end with the global winner).
__device__ __forceinline__ void argmax64(double& d, int& i, bool hi_half) {
    red_dpp<0xB1>(d, i);    // xor1  (quad_perm 1,0,3,2)
    red_dpp<0x4E>(d, i);    // xor2  (quad_perm 2,3,0,1)
    red_dpp<0x141>(d, i);   // i^7 row_half_mirror -> 8-max
    red_dpp<0x140>(d, i);   // i^15 row_mirror     -> 16-max
    red_swz16(d, i);        // xor16               -> 32-max
    red_x32(d, i, hi_half); // xor32               -> 64-max
}

__global__ __launch_bounds__(THREADS, 1)
void fps_kernel(const float* __restrict__ pts, int* __restrict__ out,
                ull* __restrict__ slots)
{
    const int bid  = blockIdx.x;
    const int g    = bid & 15;       // batch (XCD co-location swizzle)
    const int blk  = bid >> 4;       // block within batch, 0..15
    const int tid  = threadIdx.x;
    const int lane = tid & 63;
    const int wave = tid >> 6;       // 0..3
    const bool hi_half = (lane >= 32);

    const float* __restrict__ P = pts + (size_t)g * (NPTS * 3);

    // mailbox: [par][k] = coord_k|tag for k=0,1,2 (x,y,z); [3] unused pad
    __shared__ ull s_mail[2][4];

    // Pre-widened f64 coords + f64 dist.
    double xd[PPT], yd[PPT], zd[PPT], dist[PPT];
    const int base = blk * PPB;
#pragma unroll
    for (int j = 0; j < PPT; ++j) {
        const int idx = base + j * THREADS + tid;
        xd[j] = (double)P[idx * 3 + 0];
        yd[j] = (double)P[idx * 3 + 1];
        zd[j] = (double)P[idx * 3 + 2];
        dist[j] = 1e10;              // never survives iteration 0
    }
    if (tid < 8) ((ull*)s_mail)[tid] = 0ull;  // tags never 0
    __syncthreads();                 // once, before the loop

    double qx = (double)P[0], qy = (double)P[1], qz = (double)P[2];
    if (blk == 0 && tid == 0) out[g * NPOINTS] = 0;

    // adaptive poll sleep, units of 64cy (s_sleep(1)); proven start 12.
    int slp = 12;

    for (int it = 0; it < NPOINTS - 1; ++it) {
        // ---- f64 min-dist update + thread-local argmax (first-max) ----
        double bd = -1.0;
        int    bi = 0x7FFFFFFF;
        {
#pragma clang fp contract(off)
#pragma unroll
            for (int j = 0; j < PPT; ++j) {
                const double dx = xd[j] - qx;
                const double dy = yd[j] - qy;
                const double dz = zd[j] - qz;
                const double d  = (dx * dx + dy * dy) + dz * dz;
                const double nd = fmin(dist[j], d);
                dist[j] = nd;
                const bool t = nd > bd;          // strict: first-max kept
                bd = t ? nd : bd;
                bi = t ? (base + j * THREADS + tid) : bi;
            }
        }

        // ---- 64-lane argmax butterfly (DPP/permlane transport) ----
        argmax64(bd, bi, hi_half);

        const unsigned tag = (unsigned)(it + 1);
        const int par = it & 1;
        ull* rb = slots + (size_t)(par * NBATCH + g) * REGION_U64;

        // ---- this wave's quarter words (publish + own substitution) ----
        const ull B  = (ull)__double_as_longlong(bd);
        const ull TI = ((ull)tag << 16) | (ull)((unsigned)bi & 0xFFFFu);
        const ull own0 = ((B >> 32) << 32) | TI;
        const ull own1 = ((B & 0xFFFFFFFFull) << 32) | TI;

        // ---- per-wave publish via no-return atomic swap (single writer
        //      per word -> swap == store) ----
        if (lane < 2) {
            ull* dst = rb + (blk * QPB + wave) * SLOT_U64 + lane;
            const ull v = (lane == 0) ? own0 : own1;
            asm volatile("global_atomic_swap_x2 %0, %1, off"
                         :: "v"(dst), "v"(v) : "memory");
        }

        float qxf, qyf, qzf;         // this iteration's winner coords (f32)

        if (wave != 0) {
            // ---- winner coords from LDS (3 self-tagged words). This IS
            //      the rendezvous; parity leftovers carry tag it-1 ----
            ull f1, f2, f3;
            int guard = 0;
            bool okm;
            do {
                f1 = __hip_atomic_load(&s_mail[par][0], __ATOMIC_RELAXED,
                                       __HIP_MEMORY_SCOPE_WORKGROUP);
                f2 = __hip_atomic_load(&s_mail[par][1], __ATOMIC_RELAXED,
                                       __HIP_MEMORY_SCOPE_WORKGROUP);
                f3 = __hip_atomic_load(&s_mail[par][2], __ATOMIC_RELAXED,
                                       __HIP_MEMORY_SCOPE_WORKGROUP);
                okm = ((unsigned)f1 == tag) & ((unsigned)f2 == tag)
                    & ((unsigned)f3 == tag);
            } while (!okm && ++guard < (1 << 20));
            qxf = __int_as_float((int)(f1 >> 32));
            qyf = __int_as_float((int)(f2 >> 32));
            qzf = __int_as_float((int)(f3 >> 32));
        } else {
            // ---- wave0: poll all 64 quarters, lane i watches quarter i
            //      (16-B stride, contiguous 1 KB = 16 lines).
            //      Own quarter (lane == blk*4) from registers. ----
            ull* sp = rb + lane * SLOT_U64;
            const bool own = (lane == blk * QPB);
            ull l0 = own0, l1 = own1;
            bool ok = own;

            // ---- adaptive sleep: land the FIRST poll just after the
            //      straggler-visible time (controller below) ----
            for (int k2 = 0; k2 < slp; ++k2) __builtin_amdgcn_s_sleep(1);

            // ---- wave-uniform latching poll (uniform round count g1) ----
            int g1 = 0;
            bool allok = __all(ok);
            while (!allok && g1 < 32) {
                ull t0, t1;
                load_slot16(sp, t0, t1);
                const bool hit = (!ok) & TAGOK(t0) & TAGOK(t1);
                l0 = hit ? t0 : l0;
                l1 = hit ? t1 : l1;
                ok |= hit;
                allok = __all(ok);
                ++g1;
            }
            int g2 = 0;
            while (!ok) {
                // escalation: proven agent atomic-pair spin
                l0 = __hip_atomic_load(sp + 0, __ATOMIC_RELAXED,
                                       __HIP_MEMORY_SCOPE_AGENT);
                l1 = __hip_atomic_load(sp + 1, __ATOMIC_RELAXED,
                                       __HIP_MEMORY_SCOPE_AGENT);
                ok = TAGOK(l0) & TAGOK(l1);
                if (++g2 > (1 << 20)) break;   // fail loud, never hang
            }

            // ---- controller: target hit-on-round-1 with minimal sleep.
            //      Down 1 unit (64cy) on success; up ~1 RT on any miss. ----
            if (g1 <= 1) { if (slp > 2) --slp; }
            else         { slp = (slp + 14 < 44) ? slp + 14 : 44; }

            double cd = __longlong_as_double(
                (long long)(((l0 >> 32) << 32) | (l1 >> 32)));
            int    ci = (int)(l0 & 0xFFFFull);

            // ---- speculative prefetch of THIS lane's candidate coords:
            //      issued before the butterfly so the L2 hit overlaps it ----
            const int    si = ci;
            const float* pc = P + (size_t)(unsigned)si * 3;
            const float px = pc[0];
            const float py = pc[1];
            const float pz = pc[2];

            // ---- 64-quarter argmax butterfly (DPP/permlane transport) ----
            argmax64(cd, ci, hi_half);

            // ---- out write: independent of the coord chain ----
            if (lane == 0 && blk == 0) out[g * NPOINTS + it + 1] = ci;

            // ---- winning lane -> broadcast its prefetched coords.
            //      Candidate indices unique across all 64 quarters. ----
            const ull mb = __ballot(si == ci);
            const int wl = (__ffsll(mb) - 1) & 63;
            qxf = __int_as_float(
                __builtin_amdgcn_readlane(__float_as_int(px), wl));
            qyf = __int_as_float(
                __builtin_amdgcn_readlane(__float_as_int(py), wl));
            qzf = __int_as_float(
                __builtin_amdgcn_readlane(__float_as_int(pz), wl));

            // ---- LDS mailbox: 3 tagged coord words ----
            if (lane < 3) {
                const unsigned coord =
                    (lane == 0) ? (unsigned)__float_as_int(qxf)
                  : (lane == 1) ? (unsigned)__float_as_int(qyf)
                                : (unsigned)__float_as_int(qzf);
                __hip_atomic_store(&s_mail[par][lane],
                                   ((ull)coord << 32) | (ull)tag,
                                   __ATOMIC_RELAXED,
                                   __HIP_MEMORY_SCOPE_WORKGROUP);
            }
        }

        // ---- winner coords from registers/LDS; no dependent P[wi] fetch ----
        qx = (double)qxf; qy = (double)qyf; qz = (double)qzf;
    }
}

extern "C" void kernel_launch(void* const* d_in, const int* in_sizes, int n_in,
                              void* d_out, int out_size, void* d_ws, size_t ws_size,
                              hipStream_t stream) {
    (void)in_sizes; (void)n_in; (void)out_size; (void)ws_size;
    // d_in[0] = npoints (scalar, fixed 2048 per setup), d_in[1] = t_in
    const float* t_in = (const float*)d_in[1];
    int* out = (int*)d_out;
    ull* slots = (ull*)d_ws;  // 32 KB used

    dim3 grid(NBATCH * KBLK);
    dim3 block(THREADS);
    void* args[] = { (void*)&t_in, (void*)&out, (void*)&slots };
    hipLaunchCooperativeKernel((const void*)fps_kernel, grid, block, args, 0, stream);
}